// Round 6
// baseline (433.118 us; speedup 1.0000x reference)
//
#include <hip/hip_runtime.h>

#define NBINS 513
#define TFR   2048
#define NB    32
#define WIN   1024
#define HOP   256
#define PADT  384
#define OPB   524288
#define FR    8
#define FRB   4                      /* frames per batch */
#define TILES (TFR / FR)             /* 256 */
#define OLA_N (FR*HOP + WIN - HOP)   /* 2816 */
#define OLA_PAD (OLA_N + (OLA_N >> 4))
#define FSTRIDE 545
#define PIDX(i) ((i) + ((i) >> 4))
#define OIDX(o) ((o) + ((o) >> 4))
#define C45 0.70710678118654752f
#define TWOPI_1024 0.0061359231515425649f   /* 2*pi/1024 */

__device__ __forceinline__ float2 cadd(float2 a, float2 b){ return make_float2(a.x+b.x, a.y+b.y); }
__device__ __forceinline__ float2 csub(float2 a, float2 b){ return make_float2(a.x-b.x, a.y-b.y); }
__device__ __forceinline__ float2 cmul(float2 a, float2 b){ return make_float2(a.x*b.x - a.y*b.y, a.x*b.y + a.y*b.x); }

// wave-level fence: DS ops of one wave complete in order on the LDS pipe;
// this stops the compiler from reordering/caching LDS accesses across stages.
__device__ __forceinline__ void wavesync() {
    __builtin_amdgcn_wave_barrier();
    asm volatile("" ::: "memory");
}

#define BFLY8(u0,u1,u2,u3,u4,u5,u6,u7, v0,v1,v2,v3,v4,v5,v6,v7)            \
    float2 s0=cadd(u0,u4), t0=csub(u0,u4);                                  \
    float2 s1=cadd(u1,u5), t1=csub(u1,u5);                                  \
    float2 s2=cadd(u2,u6), t2=csub(u2,u6);                                  \
    float2 s3=cadd(u3,u7), t3=csub(u3,u7);                                  \
    t1 = make_float2(C45*(t1.x - t1.y),  C45*(t1.x + t1.y));                \
    t2 = make_float2(-t2.y, t2.x);                                          \
    t3 = make_float2(-C45*(t3.x + t3.y), C45*(t3.x - t3.y));                \
    float2 p0=cadd(s0,s2), p2=csub(s0,s2);                                  \
    float2 p1=cadd(s1,s3), p3=csub(s1,s3); p3 = make_float2(-p3.y, p3.x);   \
    float2 q0=cadd(t0,t2), q2=csub(t0,t2);                                  \
    float2 q1=cadd(t1,t3), q3=csub(t1,t3); q3 = make_float2(-q3.y, q3.x);   \
    float2 v0=cadd(p0,p1), v4=csub(p0,p1);                                  \
    float2 v2=cadd(p2,p3), v6=csub(p2,p3);                                  \
    float2 v1=cadd(q0,q1), v5=csub(q0,q1);                                  \
    float2 v3=cadd(q2,q3), v7=csub(q2,q3);

// radix-8 DIF stage with write-back (L = 64 or 8), i in [0,64)
template<int L>
__device__ __forceinline__ void fft_stage(float2* __restrict__ row,
                                          const float2* __restrict__ ph, int i)
{
    const int k    = i & (L - 1);
    const int base = ((i & ~(L - 1)) << 3) + k;
    float2 u0 = row[PIDX(base + 0*L)];
    float2 u1 = row[PIDX(base + 1*L)];
    float2 u2 = row[PIDX(base + 2*L)];
    float2 u3 = row[PIDX(base + 3*L)];
    float2 u4 = row[PIDX(base + 4*L)];
    float2 u5 = row[PIDX(base + 5*L)];
    float2 u6 = row[PIDX(base + 6*L)];
    float2 u7 = row[PIDX(base + 7*L)];
    BFLY8(u0,u1,u2,u3,u4,u5,u6,u7, v0,v1,v2,v3,v4,v5,v6,v7)
    const float2 w1 = ph[k * (128 / L)];
    float2 wq = w1;
    v1 = cmul(v1, wq);
    wq = cmul(wq, w1); v2 = cmul(v2, wq);
    wq = cmul(wq, w1); v3 = cmul(v3, wq);
    wq = cmul(wq, w1); v4 = cmul(v4, wq);
    wq = cmul(wq, w1); v5 = cmul(v5, wq);
    wq = cmul(wq, w1); v6 = cmul(v6, wq);
    wq = cmul(wq, w1); v7 = cmul(v7, wq);
    row[PIDX(base + 0*L)] = v0;
    row[PIDX(base + 1*L)] = v1;
    row[PIDX(base + 2*L)] = v2;
    row[PIDX(base + 3*L)] = v3;
    row[PIDX(base + 4*L)] = v4;
    row[PIDX(base + 5*L)] = v5;
    row[PIDX(base + 6*L)] = v6;
    row[PIDX(base + 7*L)] = v7;
}

// last stage (L=1) fused with window + LDS OLA (ds_add_f32).
// element j=8i+q is time sample n = 64q + 8(i&7) + (i>>3) (drev8).
__device__ __forceinline__ void fft_last_ola(const float2* __restrict__ row,
                                             const float2* __restrict__ hw,
                                             float* __restrict__ olab,
                                             int i, int fglob)
{
    float2 u0 = row[PIDX(8*i + 0)];
    float2 u1 = row[PIDX(8*i + 1)];
    float2 u2 = row[PIDX(8*i + 2)];
    float2 u3 = row[PIDX(8*i + 3)];
    float2 u4 = row[PIDX(8*i + 4)];
    float2 u5 = row[PIDX(8*i + 5)];
    float2 u6 = row[PIDX(8*i + 6)];
    float2 u7 = row[PIDX(8*i + 7)];
    BFLY8(u0,u1,u2,u3,u4,u5,u6,u7, v0,v1,v2,v3,v4,v5,v6,v7)
    const int nb  = 8*(i & 7) + (i >> 3);
    const int ob2 = fglob * 256;
#define OLA_Q(vq, q) do {                                                   \
        const int n_  = 64*(q) + nb;                                        \
        const float2 w_ = hw[n_];            /* pre-scaled by 1/512 */      \
        const int o0_ = ob2 + 2*n_;                                         \
        atomicAdd(&olab[OIDX(o0_)],     (vq).x * w_.x);                     \
        atomicAdd(&olab[OIDX(o0_ + 1)], (vq).y * w_.y);                     \
    } while (0)
    OLA_Q(v0, 0); OLA_Q(v1, 1); OLA_Q(v2, 2); OLA_Q(v3, 3);
    OLA_Q(v4, 4); OLA_Q(v5, 5); OLA_Q(v6, 6); OLA_Q(v7, 7);
#undef OLA_Q
}

__global__ __launch_bounds__(256) void zero_seams(float* __restrict__ out)
{
    const int total = NB * 257 * 768;
    for (int id = blockIdx.x * 256 + threadIdx.x; id < total; id += gridDim.x * 256) {
        const int q = id % 768;
        const int r = id / 768;
        const int s = r % 257;
        const int bb = r / 257;
        const int p  = s * 2048 + q;
        const int oi = p - PADT;
        if ((unsigned)oi < (unsigned)OPB) out[(size_t)bb * OPB + oi] = 0.f;
    }
}

__global__ __launch_bounds__(256, 4) void istft8(
    const float* __restrict__ sr, const float* __restrict__ si,
    float* __restrict__ out)
{
    __shared__ float2 stile[FRB * FSTRIDE];  // 17440 B
    __shared__ float2 ph[257];               //  2056 B  e^{+2pi i m/1024}, m<=256
    __shared__ float2 hw[512];               //  4096 B  (hann(2n), hann(2n+1))/512
    __shared__ float  olab[OLA_PAD];         // 11968 B
    __shared__ float  renv[HOP];             //  1024 B

    const int tid = threadIdx.x;
    const int bid = blockIdx.x;
    const int nwg = NB * TILES;
    const int swz = (bid & 7) * (nwg >> 3) + (bid >> 3);  // XCD-chunked (bijective)
    const int b    = swz / TILES;
    const int tile = swz % TILES;
    const int j0   = tile * FR;
    const int w    = tid >> 6;     // wave id = frame within batch
    const int l    = tid & 63;

    // ---- tables (no cross-thread deps before B1) ----
    for (int m = tid; m < 257; m += 256) {
        float sv, cv;
        sincosf(TWOPI_1024 * (float)m, &sv, &cv);
        ph[m] = make_float2(cv, sv);
    }
    for (int n = tid; n < 512; n += 256) {
        const float w0 = 0.5f - 0.5f * cosf(TWOPI_1024 * (float)(2*n));
        const float w1 = 0.5f - 0.5f * cosf(TWOPI_1024 * (float)(2*n + 1));
        hw[n] = make_float2(w0 * (1.0f/512.0f), w1 * (1.0f/512.0f));
    }
    {
        float e = 0.f;
        #pragma unroll
        for (int r = 0; r < 4; ++r) {
            // window SAMPLE index is tid + r*HOP directly (R5 bug: had 2x)
            const float wv = 0.5f - 0.5f * cosf(TWOPI_1024 * (float)(tid + r*HOP));
            e += wv * wv;
        }
        renv[tid] = 1.0f / e;
    }
    for (int m = tid; m < OLA_PAD; m += 256) olab[m] = 0.f;

    // ---- batch A staging (cols j0..j0+3) ----
    const size_t gbase = (size_t)b * NBINS * TFR + (size_t)j0;
    for (int row = tid; row < NBINS; row += 256) {
        const size_t ga = gbase + (size_t)row * TFR;
        float4 re = *(const float4*)(sr + ga);
        float4 im = *(const float4*)(si + ga);
        if (row == 0 || row == NBINS - 1) im = make_float4(0.f,0.f,0.f,0.f);
        stile[0*FSTRIDE + PIDX(row)] = make_float2(re.x, im.x);
        stile[1*FSTRIDE + PIDX(row)] = make_float2(re.y, im.y);
        stile[2*FSTRIDE + PIDX(row)] = make_float2(re.z, im.z);
        stile[3*FSTRIDE + PIDX(row)] = make_float2(re.w, im.w);
    }
    __syncthreads();                                   // B1

    for (int batch = 0; batch < 2; ++batch) {
        float2* row = &stile[w * FSTRIDE];
        // half-size trick, wave-local: lanes cover pairs k = l+64t
        #pragma unroll
        for (int t = 0; t < 4; ++t) {
            const int k = l + 64*t;                    // 0..255
            float2 Xk = row[PIDX(k)];
            float2 Xm = row[PIDX(512 - k)];
            float Ex = 0.5f*(Xk.x + Xm.x), Ey = 0.5f*(Xk.y - Xm.y);
            float Dx = 0.5f*(Xk.x - Xm.x), Dy = 0.5f*(Xk.y + Xm.y);
            float2 wt = ph[k];
            float Ox = Dx*wt.x - Dy*wt.y, Oy = Dx*wt.y + Dy*wt.x;
            row[PIDX(k)]       = make_float2(Ex - Oy, Ey + Ox);
            row[PIDX(512 - k)] = make_float2(Ex + Oy, Ox - Ey);  // k=0 -> unused slot 512
        }
        if (l == 0) {
            float2 Xc = row[PIDX(256)];
            row[PIDX(256)] = make_float2(Xc.x, -Xc.y);
        }
        wavesync();
        fft_stage<64>(row, ph, l);
        wavesync();
        fft_stage<8>(row, ph, l);
        wavesync();
        fft_last_ola(row, hw, olab, l, batch * FRB + w);

        if (batch == 0) {
            __syncthreads();                           // B2: batch-A adds done, stile free
            // batch B staging (cols j0+4..j0+7)
            for (int r2 = tid; r2 < NBINS; r2 += 256) {
                const size_t ga = gbase + (size_t)r2 * TFR + 4;
                float4 re = *(const float4*)(sr + ga);
                float4 im = *(const float4*)(si + ga);
                if (r2 == 0 || r2 == NBINS - 1) im = make_float4(0.f,0.f,0.f,0.f);
                stile[0*FSTRIDE + PIDX(r2)] = make_float2(re.x, im.x);
                stile[1*FSTRIDE + PIDX(r2)] = make_float2(re.y, im.y);
                stile[2*FSTRIDE + PIDX(r2)] = make_float2(re.z, im.z);
                stile[3*FSTRIDE + PIDX(r2)] = make_float2(re.w, im.w);
            }
            __syncthreads();                           // B3
        }
    }
    __syncthreads();                                   // B4: all adds visible

    // ---- store: interior = env-divided plain store; seams = atomicAdd ----
    const size_t ob = (size_t)b * OPB;
    const int pb = j0 * HOP;
    for (int idx = tid; idx < OLA_N; idx += 256) {
        const int p  = pb + idx;
        const int oi = p - PADT;
        if ((unsigned)oi < (unsigned)OPB) {
            const float v = olab[OIDX(idx)];
            if ((p & 2047) < 768) atomicAdd(&out[ob + oi], v);
            else                  out[ob + oi] = v * renv[p & 255];
        }
    }
}

__global__ __launch_bounds__(256) void seam_fix(float* __restrict__ out)
{
    __shared__ float wsq[WIN];
    const int tid = threadIdx.x;
    for (int m = tid; m < WIN; m += 256) {
        const float wv = 0.5f - 0.5f * cosf(TWOPI_1024 * (float)m);
        wsq[m] = wv * wv;
    }
    __syncthreads();

    const int total = NB * 257 * 768;
    for (int id = blockIdx.x * 256 + tid; id < total; id += gridDim.x * 256) {
        const int q = id % 768;
        const int r = id / 768;
        const int s = r % 257;
        const int bb = r / 257;
        const int p  = s * 2048 + q;
        const int oi = p - PADT;
        if ((unsigned)oi < (unsigned)OPB) {
            int jlo = (p - 768) >> 8; if (jlo < 0) jlo = 0;
            int jhi = p >> 8;         if (jhi > TFR - 1) jhi = TFR - 1;
            float e = 0.f;
            for (int j = jlo; j <= jhi; ++j) e += wsq[p - j * HOP];
            out[(size_t)bb * OPB + oi] /= e;
        }
    }
}

extern "C" void kernel_launch(void* const* d_in, const int* in_sizes, int n_in,
                              void* d_out, int out_size, void* d_ws, size_t ws_size,
                              hipStream_t stream) {
    const float* sr = (const float*)d_in[0];
    const float* si = (const float*)d_in[1];
    float* out = (float*)d_out;

    hipLaunchKernelGGL(zero_seams, dim3(2048), dim3(256), 0, stream, out);
    hipLaunchKernelGGL(istft8, dim3(NB * TILES), dim3(256), 0, stream, sr, si, out);
    hipLaunchKernelGGL(seam_fix, dim3(2048), dim3(256), 0, stream, out);
}

// Round 7
// 162.832 us; speedup vs baseline: 2.6599x; 2.6599x over previous
//
#include <hip/hip_runtime.h>

#define NBINS 513
#define TFR   2048
#define NB    32
#define WIN   1024
#define HOP   256
#define PADT  384
#define OPB   524288
#define FR    8
#define TILES (TFR / FR)            /* 256 */
#define FSTRIDE 545                 /* float2 per frame row, padded */
#define PIDX(i) ((i) + ((i) >> 4))
#define C45 0.70710678118654752f
#define TWOPI_1024 0.0061359231515425649f
#define SSC (1.0f / 512.0f)

__device__ __forceinline__ float2 cadd(float2 a, float2 b){ return make_float2(a.x+b.x, a.y+b.y); }
__device__ __forceinline__ float2 csub(float2 a, float2 b){ return make_float2(a.x-b.x, a.y-b.y); }
__device__ __forceinline__ float2 cmul(float2 a, float2 b){ return make_float2(a.x*b.x - a.y*b.y, a.x*b.y + a.y*b.x); }

#define BFLY8(u0,u1,u2,u3,u4,u5,u6,u7, v0,v1,v2,v3,v4,v5,v6,v7)            \
    float2 s0=cadd(u0,u4), t0=csub(u0,u4);                                  \
    float2 s1=cadd(u1,u5), t1=csub(u1,u5);                                  \
    float2 s2=cadd(u2,u6), t2=csub(u2,u6);                                  \
    float2 s3=cadd(u3,u7), t3=csub(u3,u7);                                  \
    t1 = make_float2(C45*(t1.x - t1.y),  C45*(t1.x + t1.y));                \
    t2 = make_float2(-t2.y, t2.x);                                          \
    t3 = make_float2(-C45*(t3.x + t3.y), C45*(t3.x - t3.y));                \
    float2 p0=cadd(s0,s2), p2=csub(s0,s2);                                  \
    float2 p1=cadd(s1,s3), p3=csub(s1,s3); p3 = make_float2(-p3.y, p3.x);   \
    float2 q0=cadd(t0,t2), q2=csub(t0,t2);                                  \
    float2 q1=cadd(t1,t3), q3=csub(t1,t3); q3 = make_float2(-q3.y, q3.x);   \
    float2 v0=cadd(p0,p1), v4=csub(p0,p1);                                  \
    float2 v2=cadd(p2,p3), v6=csub(p2,p3);                                  \
    float2 v1=cadd(q0,q1), v5=csub(q0,q1);                                  \
    float2 v3=cadd(q2,q3), v7=csub(q2,q3);

// In-place radix-8 DIF stage, i in [0,64). L=64,8,1; natural in, drev out.
template<int L>
__device__ __forceinline__ void fft_stage(float2* __restrict__ row,
                                          const float2* __restrict__ ph, int i)
{
    const int k    = i & (L - 1);
    const int base = ((i & ~(L - 1)) << 3) + k;
    float2 u0 = row[PIDX(base + 0*L)];
    float2 u1 = row[PIDX(base + 1*L)];
    float2 u2 = row[PIDX(base + 2*L)];
    float2 u3 = row[PIDX(base + 3*L)];
    float2 u4 = row[PIDX(base + 4*L)];
    float2 u5 = row[PIDX(base + 5*L)];
    float2 u6 = row[PIDX(base + 6*L)];
    float2 u7 = row[PIDX(base + 7*L)];
    BFLY8(u0,u1,u2,u3,u4,u5,u6,u7, v0,v1,v2,v3,v4,v5,v6,v7)
    if constexpr (L > 1) {
        const float2 w1 = ph[k * (128 / L)];
        float2 wq = w1;
        v1 = cmul(v1, wq);
        wq = cmul(wq, w1); v2 = cmul(v2, wq);
        wq = cmul(wq, w1); v3 = cmul(v3, wq);
        wq = cmul(wq, w1); v4 = cmul(v4, wq);
        wq = cmul(wq, w1); v5 = cmul(v5, wq);
        wq = cmul(wq, w1); v6 = cmul(v6, wq);
        wq = cmul(wq, w1); v7 = cmul(v7, wq);
    }
    row[PIDX(base + 0*L)] = v0;
    row[PIDX(base + 1*L)] = v1;
    row[PIDX(base + 2*L)] = v2;
    row[PIDX(base + 3*L)] = v3;
    row[PIDX(base + 4*L)] = v4;
    row[PIDX(base + 5*L)] = v5;
    row[PIDX(base + 6*L)] = v6;
    row[PIDX(base + 7*L)] = v7;
}

__global__ __launch_bounds__(256) void zero_seams(float* __restrict__ out)
{
    const int total = NB * 257 * 768;
    for (int id = blockIdx.x * 256 + threadIdx.x; id < total; id += gridDim.x * 256) {
        const int q = id % 768;
        const int r = id / 768;
        const int s = r % 257;
        const int bb = r / 257;
        const int p  = s * 2048 + q;
        const int oi = p - PADT;
        if ((unsigned)oi < (unsigned)OPB) out[(size_t)bb * OPB + oi] = 0.f;
    }
}

// R4 skeleton (8 frames, 2 butterflies/thread/stage, block barriers) +
// register-accumulator OLA (frame-invariant ownership c2&255==tid) +
// direct stores (interior env = exactly 1.5 -> *2/3; seams atomic).
__global__ __launch_bounds__(256, 4) void istft8(
    const float* __restrict__ sr, const float* __restrict__ si,
    float* __restrict__ out)
{
    __shared__ float2 stile[FR * FSTRIDE];   // 34880 B
    __shared__ float2 ph[513];               //  4104 B -> 38984 B, 4 blocks/CU

    const int tid = threadIdx.x;
    const int bid = blockIdx.x;
    const int nwg = NB * TILES;
    const int swz = (bid & 7) * (nwg >> 3) + (bid >> 3);  // XCD-chunked
    const int b    = swz / TILES;
    const int tile = swz % TILES;
    const int j0   = tile * FR;

    for (int m = tid; m < 513; m += 256) {
        float sv, cv;
        sincosf(TWOPI_1024 * (float)m, &sv, &cv);
        ph[m] = make_float2(cv, sv);
    }

    // ---- staging: all 8 cols per bin row via 2x float4 ----
    const size_t gbase = (size_t)b * NBINS * TFR + (size_t)j0;
    for (int row = tid; row < NBINS; row += 256) {
        const size_t ga = gbase + (size_t)row * TFR;
        float4 re0 = *(const float4*)(sr + ga);
        float4 im0 = *(const float4*)(si + ga);
        float4 re1 = *(const float4*)(sr + ga + 4);
        float4 im1 = *(const float4*)(si + ga + 4);
        if (row == 0 || row == NBINS - 1) {
            im0 = make_float4(0.f,0.f,0.f,0.f);
            im1 = make_float4(0.f,0.f,0.f,0.f);
        }
        const int pr = PIDX(row);
        stile[0*FSTRIDE + pr] = make_float2(re0.x, im0.x);
        stile[1*FSTRIDE + pr] = make_float2(re0.y, im0.y);
        stile[2*FSTRIDE + pr] = make_float2(re0.z, im0.z);
        stile[3*FSTRIDE + pr] = make_float2(re0.w, im0.w);
        stile[4*FSTRIDE + pr] = make_float2(re1.x, im1.x);
        stile[5*FSTRIDE + pr] = make_float2(re1.y, im1.y);
        stile[6*FSTRIDE + pr] = make_float2(re1.z, im1.z);
        stile[7*FSTRIDE + pr] = make_float2(re1.w, im1.w);
    }
    __syncthreads();                                   // B1

    // ---- half-size trick, in place, 1/512 scale folded (0.5*SSC) ----
    for (int f = 0; f < FR; ++f) {
        float2* row = &stile[f * FSTRIDE];
        const int k = tid;
        float2 Xk = row[PIDX(k)];
        float2 Xm = row[PIDX(512 - k)];
        const float h = 0.5f * SSC;
        float Ex = h*(Xk.x + Xm.x), Ey = h*(Xk.y - Xm.y);
        float Dx = h*(Xk.x - Xm.x), Dy = h*(Xk.y + Xm.y);
        float2 wt = ph[k];
        float Ox = Dx*wt.x - Dy*wt.y, Oy = Dx*wt.y + Dy*wt.x;
        row[PIDX(k)]       = make_float2(Ex - Oy, Ey + Ox);
        row[PIDX(512 - k)] = make_float2(Ex + Oy, Ox - Ey);  // k=0 -> unused slot 512
        if (tid == 0) {
            float2 Xc = row[PIDX(256)];
            row[PIDX(256)] = make_float2(Xc.x * SSC, -Xc.y * SSC);
        }
    }
    __syncthreads();                                   // B2

    // ---- 512-pt IFFT: 3 radix-8 stages, frame = tid>>5, 2 bflies/thread ----
    {
        const int f  = tid >> 5;
        float2* row  = &stile[f * FSTRIDE];
        const int i0 = tid & 31;
        fft_stage<64>(row, ph, i0);
        fft_stage<64>(row, ph, i0 + 32);
        __syncthreads();                               // B3
        fft_stage<8>(row, ph, i0);
        fft_stage<8>(row, ph, i0 + 32);
        __syncthreads();                               // B4
        fft_stage<1>(row, ph, i0);
        fft_stage<1>(row, ph, i0 + 32);
        __syncthreads();                               // B5
    }

    // ---- OLA into registers: cell c2 = f*128+n, owner c2&255 == tid ----
    float2 a0 = make_float2(0.f,0.f), a1 = a0, a2 = a0, a3 = a0, a4 = a0, a5 = a0;
    const bool tlo = (tid < 128);       // wave-coherent

#define OLA_STEP(F, KK, ACCV) do {                                          \
        const int n_ = (((F) & 1) ? ((tid + 128) & 255) : tid) + ((KK) << 8);\
        const int j_ = ((n_ & 7) << 6) | (n_ & 56) | (n_ >> 6);             \
        const float2 z_ = stile[(F)*FSTRIDE + PIDX(j_)];                    \
        const int m0_ = 2 * n_;                                             \
        const int mm0_ = (m0_ <= 512) ? m0_ : 1024 - m0_;                   \
        const int m1_ = m0_ + 1;                                            \
        const int mm1_ = (m1_ <= 512) ? m1_ : 1024 - m1_;                   \
        const float w0_ = 0.5f - 0.5f * ph[mm0_].x;                         \
        const float w1_ = 0.5f - 0.5f * ph[mm1_].x;                         \
        ACCV.x += z_.x * w0_;                                               \
        ACCV.y += z_.y * w1_;                                               \
    } while (0)

    OLA_STEP(0,0,a0); OLA_STEP(0,1,a1);
    if (tlo) { OLA_STEP(1,0,a1); OLA_STEP(1,1,a2); }
    else     { OLA_STEP(1,0,a0); OLA_STEP(1,1,a1); }
    OLA_STEP(2,0,a1); OLA_STEP(2,1,a2);
    if (tlo) { OLA_STEP(3,0,a2); OLA_STEP(3,1,a3); }
    else     { OLA_STEP(3,0,a1); OLA_STEP(3,1,a2); }
    OLA_STEP(4,0,a2); OLA_STEP(4,1,a3);
    if (tlo) { OLA_STEP(5,0,a3); OLA_STEP(5,1,a4); }
    else     { OLA_STEP(5,0,a2); OLA_STEP(5,1,a3); }
    OLA_STEP(6,0,a3); OLA_STEP(6,1,a4);
    if (tlo) { OLA_STEP(7,0,a4); OLA_STEP(7,1,a5); }
    else     { OLA_STEP(7,0,a3); OLA_STEP(7,1,a4); }
#undef OLA_STEP

    // ---- direct stores. cell g: samples idx=2(tid+256g) of this tile ----
    const size_t ob = (size_t)b * OPB;
    const int pb = tile * 2048;
#define STORE_SEAM(A, G) do {                                               \
        const int oi_ = pb + 2*(tid + 256*(G)) - PADT;                      \
        if ((unsigned)oi_ < (unsigned)OPB)       atomicAdd(&out[ob + oi_],     A.x); \
        if ((unsigned)(oi_+1) < (unsigned)OPB)   atomicAdd(&out[ob + oi_ + 1], A.y); \
    } while (0)
#define STORE_PLAIN(A, G) do {                                              \
        const int oi_ = pb + 2*(tid + 256*(G)) - PADT;                      \
        *(float2*)(out + ob + oi_) =                                        \
            make_float2(A.x * (2.0f/3.0f), A.y * (2.0f/3.0f));              \
    } while (0)

    STORE_SEAM(a0, 0);                       // idx [0,512): tile seam
    if (tlo) STORE_SEAM(a1, 1);              // idx [512,768): seam
    else     STORE_PLAIN(a1, 1);             // idx [768,1024): interior
    STORE_PLAIN(a2, 2);                      // [1024,1536)
    STORE_PLAIN(a3, 3);                      // [1536,2048)
    STORE_SEAM(a4, 4);                       // [2048,2560): next tile's seam
    if (tlo) STORE_SEAM(a5, 5);              // [2560,2816): seam
#undef STORE_SEAM
#undef STORE_PLAIN
}

__global__ __launch_bounds__(256) void seam_fix(float* __restrict__ out)
{
    __shared__ float wsq[WIN];
    const int tid = threadIdx.x;
    for (int m = tid; m < WIN; m += 256) {
        const float wv = 0.5f - 0.5f * cosf(TWOPI_1024 * (float)m);
        wsq[m] = wv * wv;
    }
    __syncthreads();

    const int total = NB * 257 * 768;
    for (int id = blockIdx.x * 256 + tid; id < total; id += gridDim.x * 256) {
        const int q = id % 768;
        const int r = id / 768;
        const int s = r % 257;
        const int bb = r / 257;
        const int p  = s * 2048 + q;
        const int oi = p - PADT;
        if ((unsigned)oi < (unsigned)OPB) {
            int jlo = (p - 768) >> 8; if (jlo < 0) jlo = 0;
            int jhi = p >> 8;         if (jhi > TFR - 1) jhi = TFR - 1;
            float e = 0.f;
            for (int j = jlo; j <= jhi; ++j) e += wsq[p - j * HOP];
            out[(size_t)bb * OPB + oi] /= e;
        }
    }
}

extern "C" void kernel_launch(void* const* d_in, const int* in_sizes, int n_in,
                              void* d_out, int out_size, void* d_ws, size_t ws_size,
                              hipStream_t stream) {
    const float* sr = (const float*)d_in[0];
    const float* si = (const float*)d_in[1];
    float* out = (float*)d_out;

    hipLaunchKernelGGL(zero_seams, dim3(2048), dim3(256), 0, stream, out);
    hipLaunchKernelGGL(istft8, dim3(NB * TILES), dim3(256), 0, stream, sr, si, out);
    hipLaunchKernelGGL(seam_fix, dim3(2048), dim3(256), 0, stream, out);
}

// Round 8
// 153.202 us; speedup vs baseline: 2.8271x; 1.0629x over previous
//
#include <hip/hip_runtime.h>

#define NBINS 513
#define TFR   2048
#define NB    32
#define WIN   1024
#define HOP   256
#define PADT  384
#define OPB   524288
#define FR    8
#define TILES (TFR / FR)            /* 256 */
#define FSTRIDE 545                 /* float2 per frame row, padded */
#define PIDX(i) ((i) + ((i) >> 4))
#define C45 0.70710678118654752f
#define TWOPI_1024 0.0061359231515425649f
/* scale: 1/512 (IFFT) * 2/3 (interior envelope 1.5 pre-divided) */
#define SSC   (1.0f / 512.0f * 2.0f / 3.0f)
#define CDLT  0.99998117528260114f   /* cos(2*pi/1024) */
#define SDLT  0.00613588464915448f   /* sin(2*pi/1024) */

__device__ __forceinline__ float2 cadd(float2 a, float2 b){ return make_float2(a.x+b.x, a.y+b.y); }
__device__ __forceinline__ float2 csub(float2 a, float2 b){ return make_float2(a.x-b.x, a.y-b.y); }
__device__ __forceinline__ float2 cmul(float2 a, float2 b){ return make_float2(a.x*b.x - a.y*b.y, a.x*b.y + a.y*b.x); }

#define BFLY8(u0,u1,u2,u3,u4,u5,u6,u7, v0,v1,v2,v3,v4,v5,v6,v7)            \
    float2 s0=cadd(u0,u4), t0=csub(u0,u4);                                  \
    float2 s1=cadd(u1,u5), t1=csub(u1,u5);                                  \
    float2 s2=cadd(u2,u6), t2=csub(u2,u6);                                  \
    float2 s3=cadd(u3,u7), t3=csub(u3,u7);                                  \
    t1 = make_float2(C45*(t1.x - t1.y),  C45*(t1.x + t1.y));                \
    t2 = make_float2(-t2.y, t2.x);                                          \
    t3 = make_float2(-C45*(t3.x + t3.y), C45*(t3.x - t3.y));                \
    float2 p0=cadd(s0,s2), p2=csub(s0,s2);                                  \
    float2 p1=cadd(s1,s3), p3=csub(s1,s3); p3 = make_float2(-p3.y, p3.x);   \
    float2 q0=cadd(t0,t2), q2=csub(t0,t2);                                  \
    float2 q1=cadd(t1,t3), q3=csub(t1,t3); q3 = make_float2(-q3.y, q3.x);   \
    float2 v0=cadd(p0,p1), v4=csub(p0,p1);                                  \
    float2 v2=cadd(p2,p3), v6=csub(p2,p3);                                  \
    float2 v1=cadd(q0,q1), v5=csub(q0,q1);                                  \
    float2 v3=cadd(q2,q3), v7=csub(q2,q3);

// In-place radix-8 DIF stage, i in [0,64). L=64,8,1; natural in, drev out.
template<int L>
__device__ __forceinline__ void fft_stage(float2* __restrict__ row,
                                          const float2* __restrict__ ph, int i)
{
    const int k    = i & (L - 1);
    const int base = ((i & ~(L - 1)) << 3) + k;
    float2 u0 = row[PIDX(base + 0*L)];
    float2 u1 = row[PIDX(base + 1*L)];
    float2 u2 = row[PIDX(base + 2*L)];
    float2 u3 = row[PIDX(base + 3*L)];
    float2 u4 = row[PIDX(base + 4*L)];
    float2 u5 = row[PIDX(base + 5*L)];
    float2 u6 = row[PIDX(base + 6*L)];
    float2 u7 = row[PIDX(base + 7*L)];
    BFLY8(u0,u1,u2,u3,u4,u5,u6,u7, v0,v1,v2,v3,v4,v5,v6,v7)
    if constexpr (L > 1) {
        const float2 w1 = ph[k * (128 / L)];
        float2 wq = w1;
        v1 = cmul(v1, wq);
        wq = cmul(wq, w1); v2 = cmul(v2, wq);
        wq = cmul(wq, w1); v3 = cmul(v3, wq);
        wq = cmul(wq, w1); v4 = cmul(v4, wq);
        wq = cmul(wq, w1); v5 = cmul(v5, wq);
        wq = cmul(wq, w1); v6 = cmul(v6, wq);
        wq = cmul(wq, w1); v7 = cmul(v7, wq);
    }
    row[PIDX(base + 0*L)] = v0;
    row[PIDX(base + 1*L)] = v1;
    row[PIDX(base + 2*L)] = v2;
    row[PIDX(base + 3*L)] = v3;
    row[PIDX(base + 4*L)] = v4;
    row[PIDX(base + 5*L)] = v5;
    row[PIDX(base + 6*L)] = v6;
    row[PIDX(base + 7*L)] = v7;
}

__global__ __launch_bounds__(256) void zero_seams(float* __restrict__ out)
{
    const int total = NB * 257 * 768;
    for (int id = blockIdx.x * 256 + threadIdx.x; id < total; id += gridDim.x * 256) {
        const int q = id % 768;
        const int r = id / 768;
        const int s = r % 257;
        const int bb = r / 257;
        const int p  = s * 2048 + q;
        const int oi = p - PADT;
        if ((unsigned)oi < (unsigned)OPB) out[(size_t)bb * OPB + oi] = 0.f;
    }
}

// Fused staging+trick in registers -> Z to LDS -> 3 radix-8 stages ->
// register-accumulator OLA (weights from one ph read via angle identities)
// -> direct stores, everything pre-divided by the interior envelope 1.5.
__global__ __launch_bounds__(256, 4) void istft8(
    const float* __restrict__ sr, const float* __restrict__ si,
    float* __restrict__ out)
{
    __shared__ float2 stile[FR * FSTRIDE];   // 34880 B
    __shared__ float2 ph[513];               //  4104 B -> 38984 B, 4 blocks/CU

    const int tid = threadIdx.x;
    const int bid = blockIdx.x;
    const int nwg = NB * TILES;
    const int swz = (bid & 7) * (nwg >> 3) + (bid >> 3);  // XCD-chunked
    const int b    = swz / TILES;
    const int tile = swz % TILES;
    const int j0   = tile * FR;

    // ---- twiddle table ----
    for (int m = tid; m < 513; m += 256) {
        float sv, cv;
        sincosf(TWOPI_1024 * (float)m, &sv, &cv);
        ph[m] = make_float2(cv, sv);
    }

    // ---- loads: row pair (tid, 512-tid); thread 0 also row 256 ----
    const size_t gbase = (size_t)b * NBINS * TFR + (size_t)j0;
    const size_t gaA = gbase + (size_t)tid * TFR;
    const size_t gaB = gbase + (size_t)(512 - tid) * TFR;
    float4 reA0 = *(const float4*)(sr + gaA);
    float4 reA1 = *(const float4*)(sr + gaA + 4);
    float4 imA0 = *(const float4*)(si + gaA);
    float4 imA1 = *(const float4*)(si + gaA + 4);
    float4 reB0 = *(const float4*)(sr + gaB);
    float4 reB1 = *(const float4*)(sr + gaB + 4);
    float4 imB0 = *(const float4*)(si + gaB);
    float4 imB1 = *(const float4*)(si + gaB + 4);
    float4 reC0, reC1, imC0, imC1;
    if (tid == 0) {
        // irfft ignores Im of bins 0 and 512
        imA0 = imA1 = imB0 = imB1 = make_float4(0.f,0.f,0.f,0.f);
        const size_t gaC = gbase + (size_t)256 * TFR;
        reC0 = *(const float4*)(sr + gaC);
        reC1 = *(const float4*)(sr + gaC + 4);
        imC0 = *(const float4*)(si + gaC);
        imC1 = *(const float4*)(si + gaC + 4);
    }
    __syncthreads();                                   // B0: ph ready

    // ---- half-size trick in registers, write Z ----
    {
        const float h = 0.5f * SSC;
        const float2 wt = ph[tid];
        const int pk  = PIDX(tid);
        const int pk2 = PIDX(512 - tid);   // tid=0 -> slot 544 (unused)
#define TRICK(F, XKX, XKY, XMX, XMY) do {                                   \
            const float Ex = h*((XKX)+(XMX)), Ey = h*((XKY)-(XMY));         \
            const float Dx = h*((XKX)-(XMX)), Dy = h*((XKY)+(XMY));         \
            const float Ox = Dx*wt.x - Dy*wt.y, Oy = Dx*wt.y + Dy*wt.x;     \
            stile[(F)*FSTRIDE + pk]  = make_float2(Ex - Oy, Ey + Ox);       \
            stile[(F)*FSTRIDE + pk2] = make_float2(Ex + Oy, Ox - Ey);       \
        } while (0)
        TRICK(0, reA0.x, imA0.x, reB0.x, imB0.x);
        TRICK(1, reA0.y, imA0.y, reB0.y, imB0.y);
        TRICK(2, reA0.z, imA0.z, reB0.z, imB0.z);
        TRICK(3, reA0.w, imA0.w, reB0.w, imB0.w);
        TRICK(4, reA1.x, imA1.x, reB1.x, imB1.x);
        TRICK(5, reA1.y, imA1.y, reB1.y, imB1.y);
        TRICK(6, reA1.z, imA1.z, reB1.z, imB1.z);
        TRICK(7, reA1.w, imA1.w, reB1.w, imB1.w);
#undef TRICK
        if (tid == 0) {   // Z[256] = conj(X[256]) * SSC
            const int pn = PIDX(256);
            stile[0*FSTRIDE + pn] = make_float2(reC0.x * SSC, -imC0.x * SSC);
            stile[1*FSTRIDE + pn] = make_float2(reC0.y * SSC, -imC0.y * SSC);
            stile[2*FSTRIDE + pn] = make_float2(reC0.z * SSC, -imC0.z * SSC);
            stile[3*FSTRIDE + pn] = make_float2(reC0.w * SSC, -imC0.w * SSC);
            stile[4*FSTRIDE + pn] = make_float2(reC1.x * SSC, -imC1.x * SSC);
            stile[5*FSTRIDE + pn] = make_float2(reC1.y * SSC, -imC1.y * SSC);
            stile[6*FSTRIDE + pn] = make_float2(reC1.z * SSC, -imC1.z * SSC);
            stile[7*FSTRIDE + pn] = make_float2(reC1.w * SSC, -imC1.w * SSC);
        }
    }
    __syncthreads();                                   // B1

    // ---- 512-pt IFFT: 3 radix-8 stages, frame = tid>>5, 2 bflies/thread ----
    {
        const int f  = tid >> 5;
        float2* row  = &stile[f * FSTRIDE];
        const int i0 = tid & 31;
        fft_stage<64>(row, ph, i0);
        fft_stage<64>(row, ph, i0 + 32);
        __syncthreads();                               // B2
        fft_stage<8>(row, ph, i0);
        fft_stage<8>(row, ph, i0 + 32);
        __syncthreads();                               // B3
        fft_stage<1>(row, ph, i0);
        fft_stage<1>(row, ph, i0 + 32);
        __syncthreads();                               // B4
    }

    // ---- OLA into registers: cell c2 = f*128+n, owner c2&255 == tid.
    // hann(2n) = 1-c^2 ; hann(2n+1) via compound angle from (c,s)=ph[n].
    float2 a0 = make_float2(0.f,0.f), a1 = a0, a2 = a0, a3 = a0, a4 = a0, a5 = a0;
    const bool tlo = (tid < 128);       // wave-coherent

#define OLA_STEP(F, KK, ACCV) do {                                          \
        const int n_ = (((F) & 1) ? ((tid + 128) & 255) : tid) + ((KK) << 8);\
        const int j_ = ((n_ & 7) << 6) | (n_ & 56) | (n_ >> 6);             \
        const float2 z_ = stile[(F)*FSTRIDE + PIDX(j_)];                    \
        const float2 cs_ = ph[n_];                                          \
        const float w0_ = 1.0f - cs_.x * cs_.x;                             \
        const float c2_ = 2.0f*cs_.x*cs_.x - 1.0f;                          \
        const float s2_ = 2.0f*cs_.x*cs_.y;                                 \
        const float w1_ = 0.5f - 0.5f*(c2_*CDLT - s2_*SDLT);                \
        ACCV.x += z_.x * w0_;                                               \
        ACCV.y += z_.y * w1_;                                               \
    } while (0)

    OLA_STEP(0,0,a0); OLA_STEP(0,1,a1);
    if (tlo) { OLA_STEP(1,0,a1); OLA_STEP(1,1,a2); }
    else     { OLA_STEP(1,0,a0); OLA_STEP(1,1,a1); }
    OLA_STEP(2,0,a1); OLA_STEP(2,1,a2);
    if (tlo) { OLA_STEP(3,0,a2); OLA_STEP(3,1,a3); }
    else     { OLA_STEP(3,0,a1); OLA_STEP(3,1,a2); }
    OLA_STEP(4,0,a2); OLA_STEP(4,1,a3);
    if (tlo) { OLA_STEP(5,0,a3); OLA_STEP(5,1,a4); }
    else     { OLA_STEP(5,0,a2); OLA_STEP(5,1,a3); }
    OLA_STEP(6,0,a3); OLA_STEP(6,1,a4);
    if (tlo) { OLA_STEP(7,0,a4); OLA_STEP(7,1,a5); }
    else     { OLA_STEP(7,0,a3); OLA_STEP(7,1,a4); }
#undef OLA_STEP

    // ---- direct stores (values already env-divided by 1.5) ----
    const size_t ob = (size_t)b * OPB;
    const int pb = tile * 2048;
#define STORE_SEAM(A, G) do {                                               \
        const int oi_ = pb + 2*(tid + 256*(G)) - PADT;                      \
        if ((unsigned)oi_ < (unsigned)OPB)       atomicAdd(&out[ob + oi_],     A.x); \
        if ((unsigned)(oi_+1) < (unsigned)OPB)   atomicAdd(&out[ob + oi_ + 1], A.y); \
    } while (0)
#define STORE_PLAIN(A, G) do {                                              \
        const int oi_ = pb + 2*(tid + 256*(G)) - PADT;                      \
        *(float2*)(out + ob + oi_) = A;                                     \
    } while (0)

    STORE_SEAM(a0, 0);
    if (tlo) STORE_SEAM(a1, 1);
    else     STORE_PLAIN(a1, 1);
    STORE_PLAIN(a2, 2);
    STORE_PLAIN(a3, 3);
    STORE_SEAM(a4, 4);
    if (tlo) STORE_SEAM(a5, 5);
#undef STORE_SEAM
#undef STORE_PLAIN
}

// env != 1.5 only within 384 samples of the global edges; rescale those.
__global__ __launch_bounds__(256) void edge_fix(float* __restrict__ out)
{
    const int id = blockIdx.x * 256 + threadIdx.x;   // 768 * NB total
    if (id >= 768 * NB) return;
    const int bb = id / 768;
    const int r  = id % 768;
    const int oi = (r < 384) ? r : (OPB - 768 + r);
    const int p  = oi + PADT;
    int jlo = (p - 768) >> 8; if (jlo < 0) jlo = 0;
    int jhi = p >> 8;         if (jhi > TFR - 1) jhi = TFR - 1;
    float e = 0.f;
    for (int j = jlo; j <= jhi; ++j) {
        const float wv = 0.5f - 0.5f * cosf(TWOPI_1024 * (float)(p - j * HOP));
        e += wv * wv;
    }
    out[(size_t)bb * OPB + oi] *= 1.5f / e;
}

extern "C" void kernel_launch(void* const* d_in, const int* in_sizes, int n_in,
                              void* d_out, int out_size, void* d_ws, size_t ws_size,
                              hipStream_t stream) {
    const float* sr = (const float*)d_in[0];
    const float* si = (const float*)d_in[1];
    float* out = (float*)d_out;

    hipLaunchKernelGGL(zero_seams, dim3(2048), dim3(256), 0, stream, out);
    hipLaunchKernelGGL(istft8, dim3(NB * TILES), dim3(256), 0, stream, sr, si, out);
    hipLaunchKernelGGL(edge_fix, dim3((768 * NB + 255) / 256), dim3(256), 0, stream, out);
}

// Round 9
// 134.446 us; speedup vs baseline: 3.2215x; 1.1395x over previous
//
#include <hip/hip_runtime.h>
#include <hip/hip_fp16.h>

#define NBINS 513
#define TFR   2048
#define NB    32
#define WIN   1024
#define HOP   256
#define PADT  384
#define OPB   524288
#define FR    8
#define TILES (TFR / FR)            /* 256 */
#define FSTRIDE 545                 /* half2 per frame row, padded */
#define PIDX(i) ((i) + ((i) >> 4))
#define C45 0.70710678118654752f
#define TWOPI_1024 0.0061359231515425649f
/* scale: 1/512 (IFFT) * 2/3 (interior envelope 1.5 pre-divided) */
#define SSC   (1.0f / 512.0f * 2.0f / 3.0f)
#define CDLT  0.99998117528260114f   /* cos(2*pi/1024) */
#define SDLT  0.00613588464915448f   /* sin(2*pi/1024) */

__device__ __forceinline__ float2 cadd(float2 a, float2 b){ return make_float2(a.x+b.x, a.y+b.y); }
__device__ __forceinline__ float2 csub(float2 a, float2 b){ return make_float2(a.x-b.x, a.y-b.y); }
__device__ __forceinline__ float2 cmul(float2 a, float2 b){ return make_float2(a.x*b.x - a.y*b.y, a.x*b.y + a.y*b.x); }

__device__ __forceinline__ float2 h2f(__half2 h){ return __half22float2(h); }
__device__ __forceinline__ __half2 f2h(float x, float y){ return __floats2half2_rn(x, y); }

#define BFLY8(u0,u1,u2,u3,u4,u5,u6,u7, v0,v1,v2,v3,v4,v5,v6,v7)            \
    float2 s0=cadd(u0,u4), t0=csub(u0,u4);                                  \
    float2 s1=cadd(u1,u5), t1=csub(u1,u5);                                  \
    float2 s2=cadd(u2,u6), t2=csub(u2,u6);                                  \
    float2 s3=cadd(u3,u7), t3=csub(u3,u7);                                  \
    t1 = make_float2(C45*(t1.x - t1.y),  C45*(t1.x + t1.y));                \
    t2 = make_float2(-t2.y, t2.x);                                          \
    t3 = make_float2(-C45*(t3.x + t3.y), C45*(t3.x - t3.y));                \
    float2 p0=cadd(s0,s2), p2=csub(s0,s2);                                  \
    float2 p1=cadd(s1,s3), p3=csub(s1,s3); p3 = make_float2(-p3.y, p3.x);   \
    float2 q0=cadd(t0,t2), q2=csub(t0,t2);                                  \
    float2 q1=cadd(t1,t3), q3=csub(t1,t3); q3 = make_float2(-q3.y, q3.x);   \
    float2 v0=cadd(p0,p1), v4=csub(p0,p1);                                  \
    float2 v2=cadd(p2,p3), v6=csub(p2,p3);                                  \
    float2 v1=cadd(q0,q1), v5=csub(q0,q1);                                  \
    float2 v3=cadd(q2,q3), v7=csub(q2,q3);

// In-place radix-8 DIF stage on f16 LDS, i in [0,64). L=64,8,1.
template<int L>
__device__ __forceinline__ void fft_stage(__half2* __restrict__ row,
                                          const float2* __restrict__ ph, int i)
{
    const int k    = i & (L - 1);
    const int base = ((i & ~(L - 1)) << 3) + k;
    float2 u0 = h2f(row[PIDX(base + 0*L)]);
    float2 u1 = h2f(row[PIDX(base + 1*L)]);
    float2 u2 = h2f(row[PIDX(base + 2*L)]);
    float2 u3 = h2f(row[PIDX(base + 3*L)]);
    float2 u4 = h2f(row[PIDX(base + 4*L)]);
    float2 u5 = h2f(row[PIDX(base + 5*L)]);
    float2 u6 = h2f(row[PIDX(base + 6*L)]);
    float2 u7 = h2f(row[PIDX(base + 7*L)]);
    BFLY8(u0,u1,u2,u3,u4,u5,u6,u7, v0,v1,v2,v3,v4,v5,v6,v7)
    if constexpr (L > 1) {
        const float2 w1 = ph[k * (128 / L)];   // idx <= 126
        float2 wq = w1;
        v1 = cmul(v1, wq);
        wq = cmul(wq, w1); v2 = cmul(v2, wq);
        wq = cmul(wq, w1); v3 = cmul(v3, wq);
        wq = cmul(wq, w1); v4 = cmul(v4, wq);
        wq = cmul(wq, w1); v5 = cmul(v5, wq);
        wq = cmul(wq, w1); v6 = cmul(v6, wq);
        wq = cmul(wq, w1); v7 = cmul(v7, wq);
    }
    row[PIDX(base + 0*L)] = f2h(v0.x, v0.y);
    row[PIDX(base + 1*L)] = f2h(v1.x, v1.y);
    row[PIDX(base + 2*L)] = f2h(v2.x, v2.y);
    row[PIDX(base + 3*L)] = f2h(v3.x, v3.y);
    row[PIDX(base + 4*L)] = f2h(v4.x, v4.y);
    row[PIDX(base + 5*L)] = f2h(v5.x, v5.y);
    row[PIDX(base + 6*L)] = f2h(v6.x, v6.y);
    row[PIDX(base + 7*L)] = f2h(v7.x, v7.y);
}

// (hann(2n), hann(2n+1)) for n in [0,512), from a 257-entry quarter table.
__device__ __forceinline__ float2 hann_pair(const float2* __restrict__ ph, int n)
{
    const bool mir = n > 256;
    const int  m   = mir ? 512 - n : n;
    const float2 cs = ph[m];
    const float c = mir ? -cs.x : cs.x;
    const float s = cs.y;
    const float w0 = 1.0f - c*c;                       // hann(2n) = 1 - cos^2
    const float c2 = 2.0f*c*c - 1.0f;                  // cos(2theta)
    const float s2 = 2.0f*c*s;                         // sin(2theta)
    const float w1 = 0.5f - 0.5f*(c2*CDLT - s2*SDLT);  // hann(2n+1)
    return make_float2(w0, w1);
}

__global__ __launch_bounds__(256) void zero_seams(float* __restrict__ out)
{
    const int total = NB * 257 * 768;
    for (int id = blockIdx.x * 256 + threadIdx.x; id < total; id += gridDim.x * 256) {
        const int q = id % 768;
        const int r = id / 768;
        const int s = r % 257;
        const int bb = r / 257;
        const int p  = s * 2048 + q;
        const int oi = p - PADT;
        if ((unsigned)oi < (unsigned)OPB) out[(size_t)bb * OPB + oi] = 0.f;
    }
}

// Fused staging+trick in registers -> f16 Z to LDS -> 3 radix-8 stages ->
// register-accumulator OLA (4 precomputed weight pairs) -> direct stores,
// everything pre-divided by the interior envelope 1.5.
__global__ __launch_bounds__(256, 8) void istft8(
    const float* __restrict__ sr, const float* __restrict__ si,
    float* __restrict__ out)
{
    __shared__ __half2 stile[FR * FSTRIDE];  // 17440 B
    __shared__ float2  ph[257];              //  2056 B -> 19496 B, 8 blocks/CU

    const int tid = threadIdx.x;
    const int bid = blockIdx.x;
    const int nwg = NB * TILES;
    const int swz = (bid & 7) * (nwg >> 3) + (bid >> 3);  // XCD-chunked
    const int b    = swz / TILES;
    const int tile = swz % TILES;
    const int j0   = tile * FR;

    // ---- twiddle quarter-table e^{+2pi i m/1024}, m in [0,256] ----
    for (int m = tid; m < 257; m += 256) {
        float sv, cv;
        sincosf(TWOPI_1024 * (float)m, &sv, &cv);
        ph[m] = make_float2(cv, sv);
    }

    // ---- loads: row pair (tid, 512-tid); thread 0 also row 256 ----
    const size_t gbase = (size_t)b * NBINS * TFR + (size_t)j0;
    const size_t gaA = gbase + (size_t)tid * TFR;
    const size_t gaB = gbase + (size_t)(512 - tid) * TFR;
    float4 reA0 = *(const float4*)(sr + gaA);
    float4 reA1 = *(const float4*)(sr + gaA + 4);
    float4 imA0 = *(const float4*)(si + gaA);
    float4 imA1 = *(const float4*)(si + gaA + 4);
    float4 reB0 = *(const float4*)(sr + gaB);
    float4 reB1 = *(const float4*)(sr + gaB + 4);
    float4 imB0 = *(const float4*)(si + gaB);
    float4 imB1 = *(const float4*)(si + gaB + 4);
    float4 reC0, reC1, imC0, imC1;
    if (tid == 0) {
        // irfft ignores Im of bins 0 and 512
        imA0 = imA1 = imB0 = imB1 = make_float4(0.f,0.f,0.f,0.f);
        const size_t gaC = gbase + (size_t)256 * TFR;
        reC0 = *(const float4*)(sr + gaC);
        reC1 = *(const float4*)(sr + gaC + 4);
        imC0 = *(const float4*)(si + gaC);
        imC1 = *(const float4*)(si + gaC + 4);
    }
    __syncthreads();                                   // B0: ph ready

    // ---- half-size trick in registers, write Z (f16) ----
    {
        const float h = 0.5f * SSC;
        const float2 wt = ph[tid];
        const int pk  = PIDX(tid);
        const int pk2 = PIDX(512 - tid);   // tid=0 -> slot 544 (unused)
#define TRICK(F, XKX, XKY, XMX, XMY) do {                                   \
            const float Ex = h*((XKX)+(XMX)), Ey = h*((XKY)-(XMY));         \
            const float Dx = h*((XKX)-(XMX)), Dy = h*((XKY)+(XMY));         \
            const float Ox = Dx*wt.x - Dy*wt.y, Oy = Dx*wt.y + Dy*wt.x;     \
            stile[(F)*FSTRIDE + pk]  = f2h(Ex - Oy, Ey + Ox);               \
            stile[(F)*FSTRIDE + pk2] = f2h(Ex + Oy, Ox - Ey);               \
        } while (0)
        TRICK(0, reA0.x, imA0.x, reB0.x, imB0.x);
        TRICK(1, reA0.y, imA0.y, reB0.y, imB0.y);
        TRICK(2, reA0.z, imA0.z, reB0.z, imB0.z);
        TRICK(3, reA0.w, imA0.w, reB0.w, imB0.w);
        TRICK(4, reA1.x, imA1.x, reB1.x, imB1.x);
        TRICK(5, reA1.y, imA1.y, reB1.y, imB1.y);
        TRICK(6, reA1.z, imA1.z, reB1.z, imB1.z);
        TRICK(7, reA1.w, imA1.w, reB1.w, imB1.w);
#undef TRICK
        if (tid == 0) {   // Z[256] = conj(X[256]) * SSC
            const int pn = PIDX(256);
            stile[0*FSTRIDE + pn] = f2h(reC0.x * SSC, -imC0.x * SSC);
            stile[1*FSTRIDE + pn] = f2h(reC0.y * SSC, -imC0.y * SSC);
            stile[2*FSTRIDE + pn] = f2h(reC0.z * SSC, -imC0.z * SSC);
            stile[3*FSTRIDE + pn] = f2h(reC0.w * SSC, -imC0.w * SSC);
            stile[4*FSTRIDE + pn] = f2h(reC1.x * SSC, -imC1.x * SSC);
            stile[5*FSTRIDE + pn] = f2h(reC1.y * SSC, -imC1.y * SSC);
            stile[6*FSTRIDE + pn] = f2h(reC1.z * SSC, -imC1.z * SSC);
            stile[7*FSTRIDE + pn] = f2h(reC1.w * SSC, -imC1.w * SSC);
        }
    }
    __syncthreads();                                   // B1

    // ---- 512-pt IFFT: 3 radix-8 stages, frame = tid>>5, 2 bflies/thread ----
    {
        const int f  = tid >> 5;
        __half2* row = &stile[f * FSTRIDE];
        const int i0 = tid & 31;
        fft_stage<64>(row, ph, i0);
        fft_stage<64>(row, ph, i0 + 32);
        __syncthreads();                               // B2
        fft_stage<8>(row, ph, i0);
        fft_stage<8>(row, ph, i0 + 32);
        __syncthreads();                               // B3
        fft_stage<1>(row, ph, i0);
        fft_stage<1>(row, ph, i0 + 32);
        __syncthreads();                               // B4
    }

    // ---- OLA into registers: cell c2 = f*128+n, owner c2&255 == tid.
    // Only 4 distinct weight pairs per thread; precompute once.
    const int nE = tid;
    const int nO = (tid + 128) & 255;
    const float2 wE0 = hann_pair(ph, nE);
    const float2 wE1 = hann_pair(ph, nE + 256);
    const float2 wO0 = hann_pair(ph, nO);
    const float2 wO1 = hann_pair(ph, nO + 256);

    float2 a0 = make_float2(0.f,0.f), a1 = a0, a2 = a0, a3 = a0, a4 = a0, a5 = a0;
    const bool tlo = (tid < 128);       // wave-coherent

#define OLA_STEP(F, KK, ACCV, W) do {                                       \
        const int n_ = (((F) & 1) ? nO : nE) + ((KK) << 8);                 \
        const int j_ = ((n_ & 7) << 6) | (n_ & 56) | (n_ >> 6);             \
        const float2 z_ = h2f(stile[(F)*FSTRIDE + PIDX(j_)]);               \
        ACCV.x += z_.x * W.x;                                               \
        ACCV.y += z_.y * W.y;                                               \
    } while (0)

    OLA_STEP(0,0,a0,wE0); OLA_STEP(0,1,a1,wE1);
    if (tlo) { OLA_STEP(1,0,a1,wO0); OLA_STEP(1,1,a2,wO1); }
    else     { OLA_STEP(1,0,a0,wO0); OLA_STEP(1,1,a1,wO1); }
    OLA_STEP(2,0,a1,wE0); OLA_STEP(2,1,a2,wE1);
    if (tlo) { OLA_STEP(3,0,a2,wO0); OLA_STEP(3,1,a3,wO1); }
    else     { OLA_STEP(3,0,a1,wO0); OLA_STEP(3,1,a2,wO1); }
    OLA_STEP(4,0,a2,wE0); OLA_STEP(4,1,a3,wE1);
    if (tlo) { OLA_STEP(5,0,a3,wO0); OLA_STEP(5,1,a4,wO1); }
    else     { OLA_STEP(5,0,a2,wO0); OLA_STEP(5,1,a3,wO1); }
    OLA_STEP(6,0,a3,wE0); OLA_STEP(6,1,a4,wE1);
    if (tlo) { OLA_STEP(7,0,a4,wO0); OLA_STEP(7,1,a5,wO1); }
    else     { OLA_STEP(7,0,a3,wO0); OLA_STEP(7,1,a4,wO1); }
#undef OLA_STEP

    // ---- direct stores (values already env-divided by 1.5) ----
    const size_t ob = (size_t)b * OPB;
    const int pb = tile * 2048;
#define STORE_SEAM(A, G) do {                                               \
        const int oi_ = pb + 2*(tid + 256*(G)) - PADT;                      \
        if ((unsigned)oi_ < (unsigned)OPB)       atomicAdd(&out[ob + oi_],     A.x); \
        if ((unsigned)(oi_+1) < (unsigned)OPB)   atomicAdd(&out[ob + oi_ + 1], A.y); \
    } while (0)
#define STORE_PLAIN(A, G) do {                                              \
        const int oi_ = pb + 2*(tid + 256*(G)) - PADT;                      \
        *(float2*)(out + ob + oi_) = A;                                     \
    } while (0)

    STORE_SEAM(a0, 0);
    if (tlo) STORE_SEAM(a1, 1);
    else     STORE_PLAIN(a1, 1);
    STORE_PLAIN(a2, 2);
    STORE_PLAIN(a3, 3);
    STORE_SEAM(a4, 4);
    if (tlo) STORE_SEAM(a5, 5);
#undef STORE_SEAM
#undef STORE_PLAIN
}

// env != 1.5 only within 384 samples of the global edges; rescale those.
__global__ __launch_bounds__(256) void edge_fix(float* __restrict__ out)
{
    const int id = blockIdx.x * 256 + threadIdx.x;   // 768 * NB total
    if (id >= 768 * NB) return;
    const int bb = id / 768;
    const int r  = id % 768;
    const int oi = (r < 384) ? r : (OPB - 768 + r);
    const int p  = oi + PADT;
    int jlo = (p - 768) >> 8; if (jlo < 0) jlo = 0;
    int jhi = p >> 8;         if (jhi > TFR - 1) jhi = TFR - 1;
    float e = 0.f;
    for (int j = jlo; j <= jhi; ++j) {
        const float wv = 0.5f - 0.5f * cosf(TWOPI_1024 * (float)(p - j * HOP));
        e += wv * wv;
    }
    out[(size_t)bb * OPB + oi] *= 1.5f / e;
}

extern "C" void kernel_launch(void* const* d_in, const int* in_sizes, int n_in,
                              void* d_out, int out_size, void* d_ws, size_t ws_size,
                              hipStream_t stream) {
    const float* sr = (const float*)d_in[0];
    const float* si = (const float*)d_in[1];
    float* out = (float*)d_out;

    hipLaunchKernelGGL(zero_seams, dim3(2048), dim3(256), 0, stream, out);
    hipLaunchKernelGGL(istft8, dim3(NB * TILES), dim3(256), 0, stream, sr, si, out);
    hipLaunchKernelGGL(edge_fix, dim3((768 * NB + 255) / 256), dim3(256), 0, stream, out);
}

// Round 10
// 109.946 us; speedup vs baseline: 3.9394x; 1.2228x over previous
//
#include <hip/hip_runtime.h>
#include <hip/hip_fp16.h>

#define NBINS 513
#define TFR   2048
#define NB    32
#define WIN   1024
#define HOP   256
#define PADT  384
#define OPB   524288
#define FR    16
#define TILES (TFR / FR)            /* 128 */
#define SPAN  (FR * HOP)            /* 4096 */
#define FSTRIDE 545                 /* half2 per frame row, padded */
#define PIDX(i) ((i) + ((i) >> 4))
#define C45 0.70710678118654752f
#define TWOPI_1024 0.0061359231515425649f
/* scale: 1/512 (IFFT) * 2/3 (interior envelope 1.5 pre-divided) */
#define SSC   (1.0f / 512.0f * 2.0f / 3.0f)
#define CDLT  0.99998117528260114f   /* cos(2*pi/1024) */
#define SDLT  0.00613588464915448f   /* sin(2*pi/1024) */

__device__ __forceinline__ float2 cadd(float2 a, float2 b){ return make_float2(a.x+b.x, a.y+b.y); }
__device__ __forceinline__ float2 csub(float2 a, float2 b){ return make_float2(a.x-b.x, a.y-b.y); }
__device__ __forceinline__ float2 cmul(float2 a, float2 b){ return make_float2(a.x*b.x - a.y*b.y, a.x*b.y + a.y*b.x); }
__device__ __forceinline__ float2 h2f(__half2 h){ return __half22float2(h); }
__device__ __forceinline__ __half2 f2h(float x, float y){ return __floats2half2_rn(x, y); }

#define BFLY8(u0,u1,u2,u3,u4,u5,u6,u7, v0,v1,v2,v3,v4,v5,v6,v7)            \
    float2 s0=cadd(u0,u4), t0=csub(u0,u4);                                  \
    float2 s1=cadd(u1,u5), t1=csub(u1,u5);                                  \
    float2 s2=cadd(u2,u6), t2=csub(u2,u6);                                  \
    float2 s3=cadd(u3,u7), t3=csub(u3,u7);                                  \
    t1 = make_float2(C45*(t1.x - t1.y),  C45*(t1.x + t1.y));                \
    t2 = make_float2(-t2.y, t2.x);                                          \
    t3 = make_float2(-C45*(t3.x + t3.y), C45*(t3.x - t3.y));                \
    float2 p0=cadd(s0,s2), p2=csub(s0,s2);                                  \
    float2 p1=cadd(s1,s3), p3=csub(s1,s3); p3 = make_float2(-p3.y, p3.x);   \
    float2 q0=cadd(t0,t2), q2=csub(t0,t2);                                  \
    float2 q1=cadd(t1,t3), q3=csub(t1,t3); q3 = make_float2(-q3.y, q3.x);   \
    float2 v0=cadd(p0,p1), v4=csub(p0,p1);                                  \
    float2 v2=cadd(p2,p3), v6=csub(p2,p3);                                  \
    float2 v1=cadd(q0,q1), v5=csub(q0,q1);                                  \
    float2 v3=cadd(q2,q3), v7=csub(q2,q3);

// In-place radix-8 DIF stage on f16 LDS, i in [0,64). L=64,8,1.
template<int L>
__device__ __forceinline__ void fft_stage(__half2* __restrict__ row,
                                          const float2* __restrict__ ph, int i)
{
    const int k    = i & (L - 1);
    const int base = ((i & ~(L - 1)) << 3) + k;
    float2 u0 = h2f(row[PIDX(base + 0*L)]);
    float2 u1 = h2f(row[PIDX(base + 1*L)]);
    float2 u2 = h2f(row[PIDX(base + 2*L)]);
    float2 u3 = h2f(row[PIDX(base + 3*L)]);
    float2 u4 = h2f(row[PIDX(base + 4*L)]);
    float2 u5 = h2f(row[PIDX(base + 5*L)]);
    float2 u6 = h2f(row[PIDX(base + 6*L)]);
    float2 u7 = h2f(row[PIDX(base + 7*L)]);
    BFLY8(u0,u1,u2,u3,u4,u5,u6,u7, v0,v1,v2,v3,v4,v5,v6,v7)
    if constexpr (L > 1) {
        const float2 w1 = ph[k * (128 / L)];   // idx <= 126
        float2 wq = w1;
        v1 = cmul(v1, wq);
        wq = cmul(wq, w1); v2 = cmul(v2, wq);
        wq = cmul(wq, w1); v3 = cmul(v3, wq);
        wq = cmul(wq, w1); v4 = cmul(v4, wq);
        wq = cmul(wq, w1); v5 = cmul(v5, wq);
        wq = cmul(wq, w1); v6 = cmul(v6, wq);
        wq = cmul(wq, w1); v7 = cmul(v7, wq);
    }
    row[PIDX(base + 0*L)] = f2h(v0.x, v0.y);
    row[PIDX(base + 1*L)] = f2h(v1.x, v1.y);
    row[PIDX(base + 2*L)] = f2h(v2.x, v2.y);
    row[PIDX(base + 3*L)] = f2h(v3.x, v3.y);
    row[PIDX(base + 4*L)] = f2h(v4.x, v4.y);
    row[PIDX(base + 5*L)] = f2h(v5.x, v5.y);
    row[PIDX(base + 6*L)] = f2h(v6.x, v6.y);
    row[PIDX(base + 7*L)] = f2h(v7.x, v7.y);
}

// (hann(2n), hann(2n+1)) for n in [0,512), from the 257-entry quarter table.
__device__ __forceinline__ float2 hann_pair(const float2* __restrict__ ph, int n)
{
    const bool mir = n > 256;
    const int  m   = mir ? 512 - n : n;
    const float2 cs = ph[m];
    const float c = mir ? -cs.x : cs.x;
    const float s = cs.y;
    const float w0 = 1.0f - c*c;
    const float c2 = 2.0f*c*c - 1.0f;
    const float s2 = 2.0f*c*s;
    const float w1 = 0.5f - 0.5f*(c2*CDLT - s2*SDLT);
    return make_float2(w0, w1);
}

__global__ __launch_bounds__(256) void zero_seams(float* __restrict__ out)
{
    const int total = NB * (TILES + 1) * 768;
    for (int id = blockIdx.x * 256 + threadIdx.x; id < total; id += gridDim.x * 256) {
        const int q = id % 768;
        const int r = id / 768;
        const int s = r % (TILES + 1);
        const int bb = r / (TILES + 1);
        const int p  = s * SPAN + q;
        const int oi = p - PADT;
        if ((unsigned)oi < (unsigned)OPB) out[(size_t)bb * OPB + oi] = 0.f;
    }
}

// One block = 16 frames = 4096-sample span. Reg staging + per-thread trick
// twiddle (no table dep) -> f16 Z in LDS -> 3 radix-8 stages (4 bflies/thread)
// -> register OLA -> direct stores pre-divided by interior envelope 1.5.
__global__ __launch_bounds__(256, 4) void istft16(
    const float* __restrict__ sr, const float* __restrict__ si,
    float* __restrict__ out)
{
    __shared__ __half2 stile[FR * FSTRIDE];  // 34880 B
    __shared__ float2  ph[257];              //  2056 B -> 36936 B, 4 blocks/CU

    const int tid = threadIdx.x;
    const int bid = blockIdx.x;
    const int nwg = NB * TILES;                           // 4096
    const int swz = (bid & 7) * (nwg >> 3) + (bid >> 3);  // XCD-chunked
    const int b    = swz / TILES;
    const int tile = swz % TILES;
    const int j0   = tile * FR;

    // ---- staging loads first (latency overlaps ph-table trig) ----
    const size_t gbase = (size_t)b * NBINS * TFR + (size_t)j0;
    const size_t gaA = gbase + (size_t)tid * TFR;
    const size_t gaB = gbase + (size_t)(512 - tid) * TFR;
    float4 rA0 = *(const float4*)(sr + gaA);
    float4 rA1 = *(const float4*)(sr + gaA + 4);
    float4 rA2 = *(const float4*)(sr + gaA + 8);
    float4 rA3 = *(const float4*)(sr + gaA + 12);
    float4 iA0 = *(const float4*)(si + gaA);
    float4 iA1 = *(const float4*)(si + gaA + 4);
    float4 iA2 = *(const float4*)(si + gaA + 8);
    float4 iA3 = *(const float4*)(si + gaA + 12);
    float4 rB0 = *(const float4*)(sr + gaB);
    float4 rB1 = *(const float4*)(sr + gaB + 4);
    float4 rB2 = *(const float4*)(sr + gaB + 8);
    float4 rB3 = *(const float4*)(sr + gaB + 12);
    float4 iB0 = *(const float4*)(si + gaB);
    float4 iB1 = *(const float4*)(si + gaB + 4);
    float4 iB2 = *(const float4*)(si + gaB + 8);
    float4 iB3 = *(const float4*)(si + gaB + 12);

    if (tid == 0) {
        // irfft ignores Im of bins 0 and 512
        const float4 z4 = make_float4(0.f,0.f,0.f,0.f);
        iA0=iA1=iA2=iA3=z4; iB0=iB1=iB2=iB3=z4;
        // bin 256: Z[256] = conj(X[256]) * SSC, written immediately
        const size_t gaC = gbase + (size_t)256 * TFR;
        float4 rC0 = *(const float4*)(sr + gaC);
        float4 rC1 = *(const float4*)(sr + gaC + 4);
        float4 rC2 = *(const float4*)(sr + gaC + 8);
        float4 rC3 = *(const float4*)(sr + gaC + 12);
        float4 iC0 = *(const float4*)(si + gaC);
        float4 iC1 = *(const float4*)(si + gaC + 4);
        float4 iC2 = *(const float4*)(si + gaC + 8);
        float4 iC3 = *(const float4*)(si + gaC + 12);
        const int pn = PIDX(256);
#define Z256(F, RC, IC, COMP) stile[(F)*FSTRIDE + pn] = f2h(RC.COMP * SSC, -IC.COMP * SSC)
        Z256(0,rC0,iC0,x);  Z256(1,rC0,iC0,y);  Z256(2,rC0,iC0,z);  Z256(3,rC0,iC0,w);
        Z256(4,rC1,iC1,x);  Z256(5,rC1,iC1,y);  Z256(6,rC1,iC1,z);  Z256(7,rC1,iC1,w);
        Z256(8,rC2,iC2,x);  Z256(9,rC2,iC2,y);  Z256(10,rC2,iC2,z); Z256(11,rC2,iC2,w);
        Z256(12,rC3,iC3,x); Z256(13,rC3,iC3,y); Z256(14,rC3,iC3,z); Z256(15,rC3,iC3,w);
#undef Z256
    }

    // ---- twiddle quarter-table (independent of loads) ----
    for (int m = tid; m < 257; m += 256) {
        float sv, cv;
        sincosf(TWOPI_1024 * (float)m, &sv, &cv);
        ph[m] = make_float2(cv, sv);
    }

    // ---- half-size trick in registers (per-thread sincos twiddle) ----
    {
        const float h = 0.5f * SSC;
        float swt, cwt;
        sincosf(TWOPI_1024 * (float)tid, &swt, &cwt);
        const int pk  = PIDX(tid);
        const int pk2 = PIDX(512 - tid);   // tid=0 -> slot 544 (unused)
#define TRICK(F, XKX, XKY, XMX, XMY) do {                                   \
            const float Ex = h*((XKX)+(XMX)), Ey = h*((XKY)-(XMY));         \
            const float Dx = h*((XKX)-(XMX)), Dy = h*((XKY)+(XMY));         \
            const float Ox = Dx*cwt - Dy*swt, Oy = Dx*swt + Dy*cwt;         \
            stile[(F)*FSTRIDE + pk]  = f2h(Ex - Oy, Ey + Ox);               \
            stile[(F)*FSTRIDE + pk2] = f2h(Ex + Oy, Ox - Ey);               \
        } while (0)
        TRICK(0,  rA0.x, iA0.x, rB0.x, iB0.x);
        TRICK(1,  rA0.y, iA0.y, rB0.y, iB0.y);
        TRICK(2,  rA0.z, iA0.z, rB0.z, iB0.z);
        TRICK(3,  rA0.w, iA0.w, rB0.w, iB0.w);
        TRICK(4,  rA1.x, iA1.x, rB1.x, iB1.x);
        TRICK(5,  rA1.y, iA1.y, rB1.y, iB1.y);
        TRICK(6,  rA1.z, iA1.z, rB1.z, iB1.z);
        TRICK(7,  rA1.w, iA1.w, rB1.w, iB1.w);
        TRICK(8,  rA2.x, iA2.x, rB2.x, iB2.x);
        TRICK(9,  rA2.y, iA2.y, rB2.y, iB2.y);
        TRICK(10, rA2.z, iA2.z, rB2.z, iB2.z);
        TRICK(11, rA2.w, iA2.w, rB2.w, iB2.w);
        TRICK(12, rA3.x, iA3.x, rB3.x, iB3.x);
        TRICK(13, rA3.y, iA3.y, rB3.y, iB3.y);
        TRICK(14, rA3.z, iA3.z, rB3.z, iB3.z);
        TRICK(15, rA3.w, iA3.w, rB3.w, iB3.w);
#undef TRICK
    }
    __syncthreads();                                   // B1

    // ---- 512-pt IFFT: 3 radix-8 stages, frame = tid>>4, 4 bflies/thread ----
    {
        const int f  = tid >> 4;
        __half2* row = &stile[f * FSTRIDE];
        const int i0 = tid & 15;
        fft_stage<64>(row, ph, i0);
        fft_stage<64>(row, ph, i0 + 16);
        fft_stage<64>(row, ph, i0 + 32);
        fft_stage<64>(row, ph, i0 + 48);
        __syncthreads();                               // B2
        fft_stage<8>(row, ph, i0);
        fft_stage<8>(row, ph, i0 + 16);
        fft_stage<8>(row, ph, i0 + 32);
        fft_stage<8>(row, ph, i0 + 48);
        __syncthreads();                               // B3
        fft_stage<1>(row, ph, i0);
        fft_stage<1>(row, ph, i0 + 16);
        fft_stage<1>(row, ph, i0 + 32);
        fft_stage<1>(row, ph, i0 + 48);
        __syncthreads();                               // B4
    }

    // ---- OLA into registers: cell c2 = f*128+n, owner c2&255 == tid ----
    const int nE = tid;
    const int nO = (tid + 128) & 255;
    const float2 wE0 = hann_pair(ph, nE);
    const float2 wE1 = hann_pair(ph, nE + 256);
    const float2 wO0 = hann_pair(ph, nO);
    const float2 wO1 = hann_pair(ph, nO + 256);

    float2 a0 = make_float2(0.f,0.f), a1=a0, a2=a0, a3=a0, a4=a0,
           a5 = a0, a6=a0, a7=a0, a8=a0, a9=a0;
    const bool tlo = (tid < 128);       // wave-coherent

#define OLA_STEP(F, KK, ACCV, W) do {                                       \
        const int n_ = (((F) & 1) ? nO : nE) + ((KK) << 8);                 \
        const int j_ = ((n_ & 7) << 6) | (n_ & 56) | (n_ >> 6);             \
        const float2 z_ = h2f(stile[(F)*FSTRIDE + PIDX(j_)]);               \
        ACCV.x += z_.x * W.x;                                               \
        ACCV.y += z_.y * W.y;                                               \
    } while (0)

    OLA_STEP(0,0,a0,wE0);  OLA_STEP(0,1,a1,wE1);
    if (tlo) { OLA_STEP(1,0,a1,wO0);  OLA_STEP(1,1,a2,wO1); }
    else     { OLA_STEP(1,0,a0,wO0);  OLA_STEP(1,1,a1,wO1); }
    OLA_STEP(2,0,a1,wE0);  OLA_STEP(2,1,a2,wE1);
    if (tlo) { OLA_STEP(3,0,a2,wO0);  OLA_STEP(3,1,a3,wO1); }
    else     { OLA_STEP(3,0,a1,wO0);  OLA_STEP(3,1,a2,wO1); }
    OLA_STEP(4,0,a2,wE0);  OLA_STEP(4,1,a3,wE1);
    if (tlo) { OLA_STEP(5,0,a3,wO0);  OLA_STEP(5,1,a4,wO1); }
    else     { OLA_STEP(5,0,a2,wO0);  OLA_STEP(5,1,a3,wO1); }
    OLA_STEP(6,0,a3,wE0);  OLA_STEP(6,1,a4,wE1);
    if (tlo) { OLA_STEP(7,0,a4,wO0);  OLA_STEP(7,1,a5,wO1); }
    else     { OLA_STEP(7,0,a3,wO0);  OLA_STEP(7,1,a4,wO1); }
    OLA_STEP(8,0,a4,wE0);  OLA_STEP(8,1,a5,wE1);
    if (tlo) { OLA_STEP(9,0,a5,wO0);  OLA_STEP(9,1,a6,wO1); }
    else     { OLA_STEP(9,0,a4,wO0);  OLA_STEP(9,1,a5,wO1); }
    OLA_STEP(10,0,a5,wE0); OLA_STEP(10,1,a6,wE1);
    if (tlo) { OLA_STEP(11,0,a6,wO0); OLA_STEP(11,1,a7,wO1); }
    else     { OLA_STEP(11,0,a5,wO0); OLA_STEP(11,1,a6,wO1); }
    OLA_STEP(12,0,a6,wE0); OLA_STEP(12,1,a7,wE1);
    if (tlo) { OLA_STEP(13,0,a7,wO0); OLA_STEP(13,1,a8,wO1); }
    else     { OLA_STEP(13,0,a6,wO0); OLA_STEP(13,1,a7,wO1); }
    OLA_STEP(14,0,a7,wE0); OLA_STEP(14,1,a8,wE1);
    if (tlo) { OLA_STEP(15,0,a8,wO0); OLA_STEP(15,1,a9,wO1); }
    else     { OLA_STEP(15,0,a7,wO0); OLA_STEP(15,1,a8,wO1); }
#undef OLA_STEP

    // ---- direct stores (values already env-divided by 1.5) ----
    const size_t ob = (size_t)b * OPB;
    const int pb = tile * SPAN;
#define STORE_SEAM(A, G) do {                                               \
        const int oi_ = pb + 2*(tid + 256*(G)) - PADT;                      \
        if ((unsigned)oi_ < (unsigned)OPB)       atomicAdd(&out[ob + oi_],     A.x); \
        if ((unsigned)(oi_+1) < (unsigned)OPB)   atomicAdd(&out[ob + oi_ + 1], A.y); \
    } while (0)
#define STORE_PLAIN(A, G) do {                                              \
        const int oi_ = pb + 2*(tid + 256*(G)) - PADT;                      \
        *(float2*)(out + ob + oi_) = A;                                     \
    } while (0)

    STORE_SEAM(a0, 0);                   // idx [0,512): head seam
    if (tlo) STORE_SEAM(a1, 1);          // [512,768): head seam
    else     STORE_PLAIN(a1, 1);         // [768,1024): interior
    STORE_PLAIN(a2, 2);
    STORE_PLAIN(a3, 3);
    STORE_PLAIN(a4, 4);
    STORE_PLAIN(a5, 5);
    STORE_PLAIN(a6, 6);
    STORE_PLAIN(a7, 7);                  // up to idx 4096
    STORE_SEAM(a8, 8);                   // [4096,4608): tail seam
    if (tlo) STORE_SEAM(a9, 9);          // [4608,4864): tail seam
#undef STORE_SEAM
#undef STORE_PLAIN
}

// env != 1.5 only within 384 samples of the global edges; rescale those.
__global__ __launch_bounds__(256) void edge_fix(float* __restrict__ out)
{
    const int id = blockIdx.x * 256 + threadIdx.x;   // 768 * NB total
    if (id >= 768 * NB) return;
    const int bb = id / 768;
    const int r  = id % 768;
    const int oi = (r < 384) ? r : (OPB - 768 + r);
    const int p  = oi + PADT;
    int jlo = (p - 768) >> 8; if (jlo < 0) jlo = 0;
    int jhi = p >> 8;         if (jhi > TFR - 1) jhi = TFR - 1;
    float e = 0.f;
    for (int j = jlo; j <= jhi; ++j) {
        const float wv = 0.5f - 0.5f * cosf(TWOPI_1024 * (float)(p - j * HOP));
        e += wv * wv;
    }
    out[(size_t)bb * OPB + oi] *= 1.5f / e;
}

extern "C" void kernel_launch(void* const* d_in, const int* in_sizes, int n_in,
                              void* d_out, int out_size, void* d_ws, size_t ws_size,
                              hipStream_t stream) {
    const float* sr = (const float*)d_in[0];
    const float* si = (const float*)d_in[1];
    float* out = (float*)d_out;

    hipLaunchKernelGGL(zero_seams, dim3(2048), dim3(256), 0, stream, out);
    hipLaunchKernelGGL(istft16, dim3(NB * TILES), dim3(256), 0, stream, sr, si, out);
    hipLaunchKernelGGL(edge_fix, dim3((768 * NB + 255) / 256), dim3(256), 0, stream, out);
}